// Round 12
// baseline (389.067 us; speedup 1.0000x reference)
//
#include <hip/hip_runtime.h>
#include <stdint.h>

#define B_ 256
#define L_ 196
#define C_ 2048
#define E_ 512
#define H_ 512
#define A_ 512
#define M_ (B_*L_)   // 50176

typedef __bf16 bf16x8 __attribute__((ext_vector_type(8)));
typedef float  f32x4  __attribute__((ext_vector_type(4)));

__device__ __forceinline__ unsigned short f2bf(float f) {
    union { float f; unsigned int u; } v; v.f = f;
    unsigned int r = 0x7FFFu + ((v.u >> 16) & 1u);
    return (unsigned short)((v.u + r) >> 16);
}

__device__ __forceinline__ unsigned int pk2(float a, float b) {
    return (unsigned int)f2bf(a) | ((unsigned int)f2bf(b) << 16);
}

__device__ __forceinline__ float tanh_fast(float x) {
    float e = __expf(2.f * x);          // inf-safe: e=inf -> 1; e=0 -> -1
    return 1.f - 2.f / (e + 1.f);
}

__device__ __forceinline__ void gload_lds16(const void* g, void* s) {
    __builtin_amdgcn_global_load_lds(
        (const __attribute__((address_space(1))) void*)g,
        (__attribute__((address_space(3))) void*)s, 16, 0, 0);
}

// ---------------- merged prep kernel ----------------
// blocks [0,1024): Wa fp32->bf16 ; [1024,3072): wcat row ; [3072,3328): xcat ;
// [3328,3584): hlin
__global__ __launch_bounds__(256) void k_prep(
    const float* __restrict__ Wa,
    const float* __restrict__ Wi, const float* __restrict__ Wh,
    const float* __restrict__ Wz, const float* __restrict__ bi,
    const float* __restrict__ bh, const float* __restrict__ bz,
    const float* __restrict__ xt, const float* __restrict__ preh,
    const float* __restrict__ Wha, const float* __restrict__ bha,
    const float* __restrict__ ba,
    unsigned short* __restrict__ wa_bf, unsigned short* __restrict__ wcat,
    float* __restrict__ bcat, unsigned short* __restrict__ xcat,
    float* __restrict__ hlin)
{
    const int bid = blockIdx.x, t = threadIdx.x;
    if (bid < 1024) {                       // Wa convert: 1M float4s? 262144 groups
        int i = bid * 256 + t;
        float4 v = ((const float4*)Wa)[i];
        ushort4 o; o.x = f2bf(v.x); o.y = f2bf(v.y); o.z = f2bf(v.z); o.w = f2bf(v.w);
        ((ushort4*)wa_bf)[i] = o;
    } else if (bid < 3072) {                // wcat row j
        int j = bid - 1024;
        for (int g = t; g < 768; g += 256) {
            int k = g * 4;
            const float* src;
            if (k < 512)       src = Wi + j*512 + k;
            else if (k < 1024) src = Wh + j*512 + (k - 512);
            else               src = Wz + j*2048 + (k - 1024);
            float4 v = *(const float4*)src;
            ushort4 o; o.x = f2bf(v.x); o.y = f2bf(v.y); o.z = f2bf(v.z); o.w = f2bf(v.w);
            *(ushort4*)(wcat + (size_t)j*3072 + k) = o;
        }
        if (t == 0) bcat[j] = bi[j] + bh[j] + bz[j];
    } else if (bid < 3328) {                // xcat b
        int b = bid - 3072;
        const float* src = (t < 128) ? (xt + b*512 + t*4) : (preh + b*512 + (t-128)*4);
        int off = (t < 128) ? (t*4) : (512 + (t-128)*4);
        float4 v = *(const float4*)src;
        ushort4 o; o.x = f2bf(v.x); o.y = f2bf(v.y); o.z = f2bf(v.z); o.w = f2bf(v.w);
        *(ushort4*)(xcat + (size_t)b*3072 + off) = o;
    } else {                                // hlin b (256 threads, 2 outputs each)
        __shared__ float ph[512];
        int b = bid - 3328;
        ph[t] = preh[b*512 + t];
        ph[t + 256] = preh[b*512 + t + 256];
        __syncthreads();
        #pragma unroll
        for (int o = 0; o < 2; ++o) {
            int a = t + o*256;
            float acc = bha[a] + ba[a];
            const float4* wrow = (const float4*)(Wha + (size_t)a*512);
            #pragma unroll 8
            for (int k4 = 0; k4 < 128; ++k4) {
                float4 v = wrow[k4];
                float4 p = *(const float4*)&ph[k4*4];
                acc += v.x*p.x + v.y*p.y + v.z*p.z + v.w*p.w;
            }
            hlin[b*512 + a] = acc;
        }
    }
}

// ---------------- fused scores GEMM ----------------
// scores[row] = bo + sum_a Wo[a] * tanh( att[row]·Wa[a] + hlin[b(row)][a] )
// r7 structure: 128 rows x 512 cols, BK=64, 512 threads (8 waves 2x4), LDS dbuf
// 2x80 KB, counted-vmcnt, XOR&7 swizzle (0 conflicts). NEW vs r7: A prefetched
// TWO epochs deep (reg sets avA/avB, loop unrolled x2) so A-loads get a full
// epoch (~10k cyc) of latency cover instead of ~700 cyc.
// Steady ledger (invariant 4 A outstanding at top):
//   ISSUE_B(kt+1)8 -> A4,B8 ; LOAD_A(kt+2)4 -> A4,B8,A4 = 16
//   COMPUTE0 ; VWAIT12 retires A(kt+1) ; PACK ; COMPUTE1 ; VWAIT4 retires B.

#define VWAIT12 asm volatile("s_waitcnt vmcnt(12)" ::: "memory")
#define VWAIT8  asm volatile("s_waitcnt vmcnt(8)"  ::: "memory")
#define VWAIT4  asm volatile("s_waitcnt vmcnt(4)"  ::: "memory")
#define VWAIT0  asm volatile("s_waitcnt vmcnt(0)"  ::: "memory")
#define LWAIT0  asm volatile("s_waitcnt lgkmcnt(0)" ::: "memory")

#define ISSUE_B(K0, LBN) do { \
    _Pragma("unroll") \
    for (int i_ = 0; i_ < 8; ++i_) \
        gload_lds16(wa + (size_t)(brow0 + i_*64)*C_ + (K0) + bpsC*8, \
                    (LBN) + (size_t)(tid + i_*512)*8); \
} while(0)

#define LOAD_A_A(K0) do { const float* ga_ = gaBase + (K0); \
    a0 = *(const float4*)(ga_);      a1 = *(const float4*)(ga_ + 4); \
    a2 = *(const float4*)(ga_ + 8);  a3 = *(const float4*)(ga_ + 12); \
} while(0)

#define LOAD_A_B(K0) do { const float* ga_ = gaBase + (K0); \
    b0 = *(const float4*)(ga_);      b1 = *(const float4*)(ga_ + 4); \
    b2 = *(const float4*)(ga_ + 8);  b3 = *(const float4*)(ga_ + 12); \
} while(0)

#define PACK_A_A(LAN) do { \
    uint4 w0_ = make_uint4(pk2(a0.x,a0.y), pk2(a0.z,a0.w), pk2(a1.x,a1.y), pk2(a1.z,a1.w)); \
    uint4 w1_ = make_uint4(pk2(a2.x,a2.y), pk2(a2.z,a2.w), pk2(a3.x,a3.y), pk2(a3.z,a3.w)); \
    *(uint4*)&(LAN)[ar*64 + ((app     ^ ars) * 8)] = w0_; \
    *(uint4*)&(LAN)[ar*64 + (((app+1) ^ ars) * 8)] = w1_; \
} while(0)

#define PACK_A_B(LAN) do { \
    uint4 w0_ = make_uint4(pk2(b0.x,b0.y), pk2(b0.z,b0.w), pk2(b1.x,b1.y), pk2(b1.z,b1.w)); \
    uint4 w1_ = make_uint4(pk2(b2.x,b2.y), pk2(b2.z,b2.w), pk2(b3.x,b3.y), pk2(b3.z,b3.w)); \
    *(uint4*)&(LAN)[ar*64 + ((app     ^ ars) * 8)] = w0_; \
    *(uint4*)&(LAN)[ar*64 + (((app+1) ^ ars) * 8)] = w1_; \
} while(0)

#define COMPUTE(KK, LA, LB) do { \
    const int c_ = (KK)*4 + lq; \
    bf16x8 af_[4]; \
    _Pragma("unroll") \
    for (int m_ = 0; m_ < 4; ++m_) { \
        int rrow_ = wr*64 + m_*16 + l16; \
        af_[m_] = *(const bf16x8*)&(LA)[rrow_*64 + ((c_ ^ (rrow_ & 7)) * 8)]; } \
    __builtin_amdgcn_s_setprio(1); \
    _Pragma("unroll") \
    for (int n_ = 0; n_ < 8; ++n_) { \
        int brow_ = wc*128 + n_*16 + l16; \
        bf16x8 bf_ = *(const bf16x8*)&(LB)[brow_*64 + ((c_ ^ (brow_ & 7)) * 8)]; \
        _Pragma("unroll") \
        for (int m_ = 0; m_ < 4; ++m_) \
            acc[m_][n_] = __builtin_amdgcn_mfma_f32_16x16x32_bf16(af_[m_], bf_, acc[m_][n_], 0, 0, 0); } \
    __builtin_amdgcn_s_setprio(0); \
} while(0)

__global__ __launch_bounds__(512, 1) void k_scores(
    const float* __restrict__ att,          // [M_][C_] fp32
    const unsigned short* __restrict__ wa,  // [A_][C_] bf16
    const float* __restrict__ hlin,         // [B_][A_]
    const float* __restrict__ wo,           // [A_]
    const float* __restrict__ bo,           // [1]
    float* __restrict__ scores)             // [M_]
{
    __shared__ unsigned short smem[81920];  // 160 KB: buf p at p*40960 (A 8192, B 32768 shorts)
    const int tid = threadIdx.x;
    const int w = tid >> 6, l = tid & 63;
    const int l16 = l & 15, lq = l >> 4;
    const int wr = w >> 2, wc = w & 3;      // wave tile: rows wr*64, cols wc*128
    const int row0 = blockIdx.x * 128;

    // A staging: thread t -> row t>>2, logical chunks app, app+1
    const int ar = tid >> 2;
    const int app = (tid & 3) * 2;
    const int ars = ar & 7;
    const float* gaBase = att + (size_t)(row0 + ar)*C_ + app*8;

    // B staging: i-th load -> wa row brow0+i*64, constant swizzled chunk bpsC
    const int brow0 = tid >> 3;
    const int bpsC = (tid & 7) ^ ((tid >> 3) & 7);

    f32x4 acc[4][8];
    #pragma unroll
    for (int m = 0; m < 4; ++m)
        #pragma unroll
        for (int n = 0; n < 8; ++n) acc[m][n] = (f32x4){0.f, 0.f, 0.f, 0.f};

    float4 a0, a1, a2, a3;   // A reg set for even-kt tiles
    float4 b0, b1, b2, b3;   // A reg set for odd-kt tiles
    unsigned short* lA0 = smem;
    unsigned short* lB0 = smem + 8192;
    unsigned short* lA1 = smem + 40960;
    unsigned short* lB1 = smem + 40960 + 8192;

    // ---- prologue: A(0),B(0),A(1) in flight; pack A(0)
    LOAD_A_A(0);            // A(0)4
    ISSUE_B(0, lB0);        // A4,B8 = 12
    LOAD_A_B(64);           // A4,B8,A4 = 16
    VWAIT12;                // retire A(0): regs ready
    PACK_A_A(lA0);
    VWAIT4;                 // retire B(0) -> LDS; A(1) rides
    LWAIT0;
    __builtin_amdgcn_s_barrier();

    // ---- steady state kt = 0..29, unrolled x2 (even: buf0 cur, odd: buf1 cur)
    for (int kt2 = 0; kt2 < 15; ++kt2) {
        const int kt = kt2 * 2;
        // even epoch kt
        ISSUE_B((kt + 1) * 64, lB1);        // A(kt+1)4,B8 = 12
        LOAD_A_A((kt + 2) * 64);            // +A4 = 16
        COMPUTE(0, lA0, lB0);
        VWAIT12;                            // retire A(kt+1) (odd -> set B)
        PACK_A_B(lA1);
        COMPUTE(1, lA0, lB0);
        VWAIT4;                             // retire B(kt+1); A(kt+2) rides
        LWAIT0;
        __builtin_amdgcn_s_barrier();
        // odd epoch kt+1
        ISSUE_B((kt + 2) * 64, lB0);
        LOAD_A_B((kt + 3) * 64);
        COMPUTE(0, lA1, lB1);
        VWAIT12;                            // retire A(kt+2) (even -> set A)
        PACK_A_A(lA0);
        COMPUTE(1, lA1, lB1);
        VWAIT4;
        LWAIT0;
        __builtin_amdgcn_s_barrier();
    }

    // ---- epoch 30: stage tile 31 (in avB from kt=29's LOAD), no new A
    {
        ISSUE_B(31 * 64, lB1);              // A(31)4,B8 = 12
        COMPUTE(0, lA0, lB0);
        VWAIT8;                             // retire A(31)
        PACK_A_B(lA1);
        COMPUTE(1, lA0, lB0);
        VWAIT0;
        LWAIT0;
        __builtin_amdgcn_s_barrier();
    }

    // ---- epoch 31: compute only (buf1)
    COMPUTE(0, lA1, lB1);
    COMPUTE(1, lA1, lB1);

    __syncthreads();                 // all LDS reads done; safe to alias red
    float* red = (float*)smem;       // [4 wc][128 rows]

    // epilogue: tanh + dot(Wo) + reduce
    const int colbase = wc*128 + l16;
    float won[8], hlA[8], hlB[8];
    const int bA = row0 / L_;
    const int bB = (row0 + 127) / L_;
    const int rsplit = (bA + 1) * L_;
    #pragma unroll
    for (int n = 0; n < 8; ++n) {
        won[n] = wo[colbase + n*16];
        hlA[n] = hlin[bA*A_ + colbase + n*16];
        hlB[n] = hlin[bB*A_ + colbase + n*16];
    }

    #pragma unroll
    for (int m = 0; m < 4; ++m) {
        #pragma unroll
        for (int r = 0; r < 4; ++r) {
            int lrow = wr*64 + m*16 + lq*4 + r;
            int grow = row0 + lrow;
            bool useB = grow >= rsplit;
            float s = 0.f;
            #pragma unroll
            for (int n = 0; n < 8; ++n) {
                float v = acc[m][n][r] + (useB ? hlB[n] : hlA[n]);
                s += tanh_fast(v) * won[n];
            }
            s += __shfl_xor(s, 1);
            s += __shfl_xor(s, 2);
            s += __shfl_xor(s, 4);
            s += __shfl_xor(s, 8);
            if (l16 == 0) red[wc*128 + lrow] = s;
        }
    }
    __syncthreads();
    if (tid < 128) {
        scores[row0 + tid] = red[tid] + red[128 + tid] + red[256 + tid] + red[384 + tid] + bo[0];
    }
}

// ---------------- softmax over L per batch ----------------
__global__ void k_softmax(const float* __restrict__ scores, float* __restrict__ cw) {
    __shared__ float sm[4], ss[4];
    int b = blockIdx.x, t = threadIdx.x, w = t >> 6, l = t & 63;
    float v = (t < L_) ? scores[b*L_ + t] : -1e30f;
    float m = v;
    #pragma unroll
    for (int o = 1; o < 64; o <<= 1) m = fmaxf(m, __shfl_xor(m, o));
    if (l == 0) sm[w] = m;
    __syncthreads();
    m = fmaxf(fmaxf(sm[0], sm[1]), fmaxf(sm[2], sm[3]));
    float e = (t < L_) ? expf(v - m) : 0.f;
    float s = e;
    #pragma unroll
    for (int o = 1; o < 64; o <<= 1) s += __shfl_xor(s, o);
    if (l == 0) ss[w] = s;
    __syncthreads();
    s = ss[0] + ss[1] + ss[2] + ss[3];
    if (t < L_) cw[b*L_ + t] = e / s;
}

// ---------------- z = sum_l cw[b][l]*att[b][l][:] -> xcat bf16 ----------------
__global__ void k_z(const float* __restrict__ att, const float* __restrict__ cw,
                    unsigned short* __restrict__ xcat) {
    __shared__ float w_s[L_];
    int b = blockIdx.y, half = blockIdx.x, t = threadIdx.x;
    if (t < L_) w_s[t] = cw[b*L_ + t];
    __syncthreads();
    int c = half*1024 + t*4;
    const float* base = att + (size_t)b*L_*C_ + c;
    float ax = 0.f, ay = 0.f, az = 0.f, aw = 0.f;
    #pragma unroll 4
    for (int li = 0; li < L_; ++li) {
        float4 v = *(const float4*)(base + (size_t)li*C_);
        float wt = w_s[li];
        ax += wt*v.x; ay += wt*v.y; az += wt*v.z; aw += wt*v.w;
    }
    ushort4 o; o.x = f2bf(ax); o.y = f2bf(ay); o.z = f2bf(az); o.w = f2bf(aw);
    *(ushort4*)(xcat + (size_t)b*3072 + 1024 + c) = o;
}

// ---------------- GEMM2: Sp[half] = xcat @ wcat^T (split-K), BK=64, gload_lds
__global__ __launch_bounds__(256) void k_gemm2(
    const unsigned short* __restrict__ xcat,  // [256][3072] bf16
    const unsigned short* __restrict__ wcat,  // [2048][3072] bf16
    float* __restrict__ Sp)                   // [2][256][2048]
{
    __shared__ unsigned short smem[12288];    // lA 64x64 (4096) + lB 128x64 (8192)
    unsigned short* lA = smem;
    unsigned short* lB = smem + 4096;
    const int tid = threadIdx.x;
    const int w = tid >> 6, l = tid & 63;
    const int l16 = l & 15, lq = l >> 4;
    const int wr = w >> 1, wc = w & 1;        // wave tile 32x64
    const int row0 = blockIdx.y * 64;
    const int col0 = blockIdx.x * 128;
    const int half = blockIdx.z;
    const int kbase = half * 1536;

    f32x4 acc[2][4];
    #pragma unroll
    for (int m = 0; m < 2; ++m)
        #pragma unroll
        for (int n = 0; n < 4; ++n) acc[m][n] = (f32x4){0.f, 0.f, 0.f, 0.f};

    for (int kt = 0; kt < 24; ++kt) {
        const int k0 = kbase + kt * 64;
        __syncthreads();
        #pragma unroll
        for (int i = 0; i < 2; ++i) {         // A: 512 chunks
            int g = tid + i*256;
            int r = g >> 3, c = (g & 7) ^ (r & 7);
            gload_lds16(xcat + (size_t)(row0 + r)*3072 + k0 + c*8, lA + (size_t)g*8);
        }
        #pragma unroll
        for (int i = 0; i < 4; ++i) {         // B: 1024 chunks
            int g = tid + i*256;
            int r = g >> 3, c = (g & 7) ^ (r & 7);
            gload_lds16(wcat + (size_t)(col0 + r)*3072 + k0 + c*8, lB + (size_t)g*8);
        }
        __syncthreads();                      // compiler drains vmcnt before barrier

        #pragma unroll
        for (int kk = 0; kk < 2; ++kk) {
            const int c = kk*4 + lq;
            bf16x8 af[2];
            #pragma unroll
            for (int m = 0; m < 2; ++m) {
                int rrow = wr*32 + m*16 + l16;
                af[m] = *(const bf16x8*)&lA[rrow*64 + ((c ^ (rrow & 7)) * 8)];
            }
            #pragma unroll
            for (int n = 0; n < 4; ++n) {
                int brow = wc*64 + n*16 + l16;
                bf16x8 bfr = *(const bf16x8*)&lB[brow*64 + ((c ^ (brow & 7)) * 8)];
                #pragma unroll
                for (int m = 0; m < 2; ++m)
                    acc[m][n] = __builtin_amdgcn_mfma_f32_16x16x32_bf16(af[m], bfr, acc[m][n], 0, 0, 0);
            }
        }
    }

    #pragma unroll
    for (int m = 0; m < 2; ++m)
        #pragma unroll
        for (int n = 0; n < 4; ++n)
            #pragma unroll
            for (int r = 0; r < 4; ++r) {
                int grow = row0 + wr*32 + m*16 + lq*4 + r;
                int col = col0 + wc*64 + n*16 + l16;
                Sp[(size_t)half*524288 + (size_t)grow*2048 + col] = acc[m][n][r];
            }
}

// ---------------- LSTM gates (sums split-K partials + bias) ----------------
__global__ void k_lstm(const float* __restrict__ Sp, const float* __restrict__ bcat,
                       const float* __restrict__ prec, float* __restrict__ out) {
    int b = blockIdx.x, h = threadIdx.x;  // 512 threads
    const float* S0 = Sp;
    const float* S1 = Sp + 524288;
    size_t base = (size_t)b*2048;
    float si = S0[base + h]        + S1[base + h]        + bcat[h];
    float sf = S0[base + 512 + h]  + S1[base + 512 + h]  + bcat[512 + h];
    float so = S0[base + 1024 + h] + S1[base + 1024 + h] + bcat[1024 + h];
    float sg = S0[base + 1536 + h] + S1[base + 1536 + h] + bcat[1536 + h];
    float ig = 1.f / (1.f + expf(-si));
    float fg = 1.f / (1.f + expf(-sf));
    float og = 1.f / (1.f + expf(-so));
    float gt = tanhf(sg);
    float c = fg * prec[b*512 + h] + ig * gt;
    out[b*512 + h] = og * tanhf(c);
    out[131072 + b*512 + h] = c;
}

// ---------------- launch ----------------
extern "C" void kernel_launch(void* const* d_in, const int* in_sizes, int n_in,
                              void* d_out, int out_size, void* d_ws, size_t ws_size,
                              hipStream_t stream) {
    const float* xt  = (const float*)d_in[0];
    const float* att = (const float*)d_in[1];
    const float* h0  = (const float*)d_in[2];
    const float* c0  = (const float*)d_in[3];
    const float* Wi  = (const float*)d_in[4];
    const float* bi  = (const float*)d_in[5];
    const float* Wh  = (const float*)d_in[6];
    const float* bh  = (const float*)d_in[7];
    const float* Wz  = (const float*)d_in[8];
    const float* bz  = (const float*)d_in[9];
    const float* Wa  = (const float*)d_in[10];
    const float* ba  = (const float*)d_in[11];
    const float* Wha = (const float*)d_in[12];
    const float* bha = (const float*)d_in[13];
    const float* Wo  = (const float*)d_in[14];
    const float* bo  = (const float*)d_in[15];
    float* out = (float*)d_out;

    char* ws = (char*)d_ws;
    unsigned short* wa_bf   = (unsigned short*)(ws);                       // 2 MB
    unsigned short* wcat_bf = (unsigned short*)(ws + 2097152);             // 12 MB
    unsigned short* xcat_bf = (unsigned short*)(ws + 14680064);            // 1.5 MB
    float* hlin   = (float*)(ws + 16252928);                               // 512 KB
    float* scores = (float*)(ws + 16777216);                               // 200 KB
    float* cw     = (float*)(ws + 16977920);                               // 200 KB
    float* bcat   = (float*)(ws + 17178624);                               // 8 KB
    float* Sp     = (float*)(ws + 17186816);                               // 4 MB [2][256][2048]

    k_prep<<<3584, 256, 0, stream>>>(Wa, Wi, Wh, Wz, bi, bh, bz, xt, h0,
                                     Wha, bha, ba, wa_bf, wcat_bf, bcat, xcat_bf, hlin);
    k_scores<<<M_/128, 512, 0, stream>>>(att, wa_bf, hlin, Wo, bo, scores);
    k_softmax<<<256, 256, 0, stream>>>(scores, cw);
    k_z<<<dim3(2, 256), 256, 0, stream>>>(att, cw, xcat_bf);
    k_gemm2<<<dim3(16, 4, 2), 256, 0, stream>>>(xcat_bf, wcat_bf, Sp);
    k_lstm<<<256, 512, 0, stream>>>(Sp, bcat, c0, out);
}

// Round 13
// 331.518 us; speedup vs baseline: 1.1736x; 1.1736x over previous
//
#include <hip/hip_runtime.h>
#include <stdint.h>

#define B_ 256
#define L_ 196
#define C_ 2048
#define E_ 512
#define H_ 512
#define A_ 512
#define M_ (B_*L_)   // 50176

typedef __bf16 bf16x8 __attribute__((ext_vector_type(8)));
typedef float  f32x4  __attribute__((ext_vector_type(4)));

__device__ __forceinline__ unsigned short f2bf(float f) {
    union { float f; unsigned int u; } v; v.f = f;
    unsigned int r = 0x7FFFu + ((v.u >> 16) & 1u);
    return (unsigned short)((v.u + r) >> 16);
}

__device__ __forceinline__ unsigned int pk2(float a, float b) {
    return (unsigned int)f2bf(a) | ((unsigned int)f2bf(b) << 16);
}

__device__ __forceinline__ float tanh_fast(float x) {
    float e = __expf(2.f * x);          // inf-safe: e=inf -> 1; e=0 -> -1
    return 1.f - 2.f / (e + 1.f);
}

__device__ __forceinline__ void gload_lds16(const void* g, void* s) {
    __builtin_amdgcn_global_load_lds(
        (const __attribute__((address_space(1))) void*)g,
        (__attribute__((address_space(3))) void*)s, 16, 0, 0);
}

// ---------------- prep kernels (r7-exact) ----------------

__global__ void k_cvt(const float* __restrict__ src, unsigned short* __restrict__ dst, int n4) {
    int i = blockIdx.x * blockDim.x + threadIdx.x;
    if (i < n4) {
        float4 v = ((const float4*)src)[i];
        ushort4 o; o.x = f2bf(v.x); o.y = f2bf(v.y); o.z = f2bf(v.z); o.w = f2bf(v.w);
        ((ushort4*)dst)[i] = o;
    }
}

__global__ void k_build_wcat(const float* __restrict__ Wi, const float* __restrict__ Wh,
                             const float* __restrict__ Wz, const float* __restrict__ bi,
                             const float* __restrict__ bh, const float* __restrict__ bz,
                             unsigned short* __restrict__ wcat, float* __restrict__ bcat) {
    int j = blockIdx.x;       // 2048
    int t = threadIdx.x;      // 256
    for (int g = t; g < 768; g += 256) {
        int k = g * 4;
        const float* src;
        if (k < 512)       src = Wi + j*512 + k;
        else if (k < 1024) src = Wh + j*512 + (k - 512);
        else               src = Wz + j*2048 + (k - 1024);
        float4 v = *(const float4*)src;
        ushort4 o; o.x = f2bf(v.x); o.y = f2bf(v.y); o.z = f2bf(v.z); o.w = f2bf(v.w);
        *(ushort4*)(wcat + (size_t)j*3072 + k) = o;
    }
    if (t == 0) bcat[j] = bi[j] + bh[j] + bz[j];
}

__global__ void k_build_xcat(const float* __restrict__ xt, const float* __restrict__ preh,
                             unsigned short* __restrict__ xcat) {
    int b = blockIdx.x, t = threadIdx.x;  // 256 threads
    const float* src = (t < 128) ? (xt + b*512 + t*4) : (preh + b*512 + (t-128)*4);
    int off = (t < 128) ? (t*4) : (512 + (t-128)*4);
    float4 v = *(const float4*)src;
    ushort4 o; o.x = f2bf(v.x); o.y = f2bf(v.y); o.z = f2bf(v.z); o.w = f2bf(v.w);
    *(ushort4*)(xcat + (size_t)b*3072 + off) = o;
}

__global__ void k_hlin(const float* __restrict__ preh, const float* __restrict__ Wha,
                       const float* __restrict__ bha, const float* __restrict__ ba,
                       float* __restrict__ hlin) {
    __shared__ float ph[512];
    int b = blockIdx.x, t = threadIdx.x;   // 512 threads
    ph[t] = preh[b*512 + t];
    __syncthreads();
    float acc = bha[t] + ba[t];
    const float4* wrow = (const float4*)(Wha + (size_t)t*512);
    #pragma unroll 8
    for (int k4 = 0; k4 < 128; ++k4) {
        float4 v = wrow[k4];
        float4 p = *(const float4*)&ph[k4*4];
        acc += v.x*p.x + v.y*p.y + v.z*p.z + v.w*p.w;
    }
    hlin[b*512 + t] = acc;
}

// ---------------- fused scores GEMM (r7-exact, best measured ~203 µs) ----------------
// 128 rows x 512 cols, BK=64, 512 threads (8 waves 2x4), LDS dbuf 2x80 KB,
// counted-vmcnt pipeline with raw s_barrier, XOR&7 swizzle (0 conflicts).

#define VWAIT8 asm volatile("s_waitcnt vmcnt(8)" ::: "memory")
#define VWAIT4 asm volatile("s_waitcnt vmcnt(4)" ::: "memory")
#define VWAIT0 asm volatile("s_waitcnt vmcnt(0)" ::: "memory")
#define LWAIT0 asm volatile("s_waitcnt lgkmcnt(0)" ::: "memory")

#define ISSUE_B(K0, LBN) do { \
    _Pragma("unroll") \
    for (int i_ = 0; i_ < 8; ++i_) \
        gload_lds16(wa + (size_t)(brow0 + i_*64)*C_ + (K0) + bpsC*8, \
                    (LBN) + (size_t)(tid + i_*512)*8); \
} while(0)

#define LOAD_A(K0) do { const float* ga_ = gaBase + (K0); \
    av0 = *(const float4*)(ga_);      av1 = *(const float4*)(ga_ + 4); \
    av2 = *(const float4*)(ga_ + 8);  av3 = *(const float4*)(ga_ + 12); \
} while(0)

#define PACK_A(LAN) do { \
    uint4 w0_ = make_uint4(pk2(av0.x,av0.y), pk2(av0.z,av0.w), pk2(av1.x,av1.y), pk2(av1.z,av1.w)); \
    uint4 w1_ = make_uint4(pk2(av2.x,av2.y), pk2(av2.z,av2.w), pk2(av3.x,av3.y), pk2(av3.z,av3.w)); \
    *(uint4*)&(LAN)[ar*64 + ((app     ^ ars) * 8)] = w0_; \
    *(uint4*)&(LAN)[ar*64 + (((app+1) ^ ars) * 8)] = w1_; \
} while(0)

#define COMPUTE(KK, LA, LB) do { \
    const int c_ = (KK)*4 + lq; \
    bf16x8 af_[4]; \
    _Pragma("unroll") \
    for (int m_ = 0; m_ < 4; ++m_) { \
        int rrow_ = wr*64 + m_*16 + l16; \
        af_[m_] = *(const bf16x8*)&(LA)[rrow_*64 + ((c_ ^ (rrow_ & 7)) * 8)]; } \
    __builtin_amdgcn_s_setprio(1); \
    _Pragma("unroll") \
    for (int n_ = 0; n_ < 8; ++n_) { \
        int brow_ = wc*128 + n_*16 + l16; \
        bf16x8 bf_ = *(const bf16x8*)&(LB)[brow_*64 + ((c_ ^ (brow_ & 7)) * 8)]; \
        _Pragma("unroll") \
        for (int m_ = 0; m_ < 4; ++m_) \
            acc[m_][n_] = __builtin_amdgcn_mfma_f32_16x16x32_bf16(af_[m_], bf_, acc[m_][n_], 0, 0, 0); } \
    __builtin_amdgcn_s_setprio(0); \
} while(0)

__global__ __launch_bounds__(512, 1) void k_scores(
    const float* __restrict__ att,          // [M_][C_] fp32
    const unsigned short* __restrict__ wa,  // [A_][C_] bf16
    const float* __restrict__ hlin,         // [B_][A_]
    const float* __restrict__ wo,           // [A_]
    const float* __restrict__ bo,           // [1]
    float* __restrict__ scores)             // [M_]
{
    __shared__ unsigned short smem[81920];  // 160 KB: buf p at p*40960 (A 8192, B 32768 shorts)
    const int tid = threadIdx.x;
    const int w = tid >> 6, l = tid & 63;
    const int l16 = l & 15, lq = l >> 4;
    const int wr = w >> 2, wc = w & 3;      // wave tile: rows wr*64, cols wc*128
    const int row0 = blockIdx.x * 128;

    // A staging: thread t -> row t>>2, logical chunks app, app+1
    const int ar = tid >> 2;
    const int app = (tid & 3) * 2;
    const int ars = ar & 7;
    const float* gaBase = att + (size_t)(row0 + ar)*C_ + app*8;

    // B staging: i-th load -> wa row brow0+i*64, constant swizzled chunk bpsC
    const int brow0 = tid >> 3;
    const int bpsC = (tid & 7) ^ ((tid >> 3) & 7);

    f32x4 acc[4][8];
    #pragma unroll
    for (int m = 0; m < 4; ++m)
        #pragma unroll
        for (int n = 0; n < 8; ++n) acc[m][n] = (f32x4){0.f, 0.f, 0.f, 0.f};

    float4 av0, av1, av2, av3;
    unsigned short* lA0 = smem;
    unsigned short* lB0 = smem + 8192;
    unsigned short* lA1 = smem + 40960;
    unsigned short* lB1 = smem + 40960 + 8192;

    // ---- prologue: stage tile 0 into buf0, issue A(1)
    LOAD_A(0);
    ISSUE_B(0, lB0);
    VWAIT8;                 // A(0) regs landed; 8 B gloads outstanding
    PACK_A(lA0);
    LOAD_A(64);             // outstanding = 8 B + 4 A
    VWAIT4;                 // B(0) in LDS; A(1) stays in flight
    LWAIT0;
    __builtin_amdgcn_s_barrier();

    // ---- steady state: kt = 0..29
    for (int kt = 0; kt < 30; ++kt) {
        unsigned short* lA  = (kt & 1) ? lA1 : lA0;
        unsigned short* lB  = (kt & 1) ? lB1 : lB0;
        unsigned short* lAn = (kt & 1) ? lA0 : lA1;
        unsigned short* lBn = (kt & 1) ? lB0 : lB1;
        ISSUE_B((kt + 1) * 64, lBn);        // outstanding: 4 A(kt+1) + 8 B(kt+1)
        COMPUTE(0, lA, lB);
        VWAIT8;                             // A(kt+1) regs ready
        PACK_A(lAn);
        COMPUTE(1, lA, lB);
        LOAD_A((kt + 2) * 64);              // outstanding: 8 B + 4 A(kt+2)
        VWAIT4;                             // B(kt+1) in LDS; A(kt+2) flying
        LWAIT0;
        __builtin_amdgcn_s_barrier();
    }

    // ---- kt = 30: stage tile 31, no further A prefetch
    {
        ISSUE_B(31 * 64, lB1);              // cur = buf0 (30&1==0)
        COMPUTE(0, lA0, lB0);
        VWAIT8;                             // A(31) regs ready
        PACK_A(lA1);
        COMPUTE(1, lA0, lB0);
        VWAIT0;
        LWAIT0;
        __builtin_amdgcn_s_barrier();
    }

    // ---- kt = 31: compute only (buf1)
    COMPUTE(0, lA1, lB1);
    COMPUTE(1, lA1, lB1);

    __syncthreads();                 // all LDS reads done; safe to alias red
    float* red = (float*)smem;       // [4 wc][128 rows]

    // epilogue: tanh + dot(Wo) + reduce
    const int colbase = wc*128 + l16;
    float won[8], hlA[8], hlB[8];
    const int bA = row0 / L_;
    const int bB = (row0 + 127) / L_;
    const int rsplit = (bA + 1) * L_;
    #pragma unroll
    for (int n = 0; n < 8; ++n) {
        won[n] = wo[colbase + n*16];
        hlA[n] = hlin[bA*A_ + colbase + n*16];
        hlB[n] = hlin[bB*A_ + colbase + n*16];
    }

    #pragma unroll
    for (int m = 0; m < 4; ++m) {
        #pragma unroll
        for (int r = 0; r < 4; ++r) {
            int lrow = wr*64 + m*16 + lq*4 + r;
            int grow = row0 + lrow;
            bool useB = grow >= rsplit;
            float s = 0.f;
            #pragma unroll
            for (int n = 0; n < 8; ++n) {
                float v = acc[m][n][r] + (useB ? hlB[n] : hlA[n]);
                s += tanh_fast(v) * won[n];
            }
            s += __shfl_xor(s, 1);
            s += __shfl_xor(s, 2);
            s += __shfl_xor(s, 4);
            s += __shfl_xor(s, 8);
            if (l16 == 0) red[wc*128 + lrow] = s;
        }
    }
    __syncthreads();
    if (tid < 128) {
        scores[row0 + tid] = red[tid] + red[128 + tid] + red[256 + tid] + red[384 + tid] + bo[0];
    }
}

// ---------------- softmax over L per batch ----------------
__global__ void k_softmax(const float* __restrict__ scores, float* __restrict__ cw) {
    __shared__ float sm[4], ss[4];
    int b = blockIdx.x, t = threadIdx.x, w = t >> 6, l = t & 63;
    float v = (t < L_) ? scores[b*L_ + t] : -1e30f;
    float m = v;
    #pragma unroll
    for (int o = 1; o < 64; o <<= 1) m = fmaxf(m, __shfl_xor(m, o));
    if (l == 0) sm[w] = m;
    __syncthreads();
    m = fmaxf(fmaxf(sm[0], sm[1]), fmaxf(sm[2], sm[3]));
    float e = (t < L_) ? expf(v - m) : 0.f;
    float s = e;
    #pragma unroll
    for (int o = 1; o < 64; o <<= 1) s += __shfl_xor(s, o);
    if (l == 0) ss[w] = s;
    __syncthreads();
    s = ss[0] + ss[1] + ss[2] + ss[3];
    if (t < L_) cw[b*L_ + t] = e / s;
}

// ---------------- z = sum_l cw[b][l]*att[b][l][:] -> xcat bf16 ----------------
__global__ void k_z(const float* __restrict__ att, const float* __restrict__ cw,
                    unsigned short* __restrict__ xcat) {
    __shared__ float w_s[L_];
    int b = blockIdx.y, half = blockIdx.x, t = threadIdx.x;
    if (t < L_) w_s[t] = cw[b*L_ + t];
    __syncthreads();
    int c = half*1024 + t*4;
    const float* base = att + (size_t)b*L_*C_ + c;
    float ax = 0.f, ay = 0.f, az = 0.f, aw = 0.f;
    #pragma unroll 4
    for (int li = 0; li < L_; ++li) {
        float4 v = *(const float4*)(base + (size_t)li*C_);
        float wt = w_s[li];
        ax += wt*v.x; ay += wt*v.y; az += wt*v.z; aw += wt*v.w;
    }
    ushort4 o; o.x = f2bf(ax); o.y = f2bf(ay); o.z = f2bf(az); o.w = f2bf(aw);
    *(ushort4*)(xcat + (size_t)b*3072 + 1024 + c) = o;
}

// ---------------- GEMM2: S = xcat @ wcat^T + bcat (BK=64, swizzled) ----------------
__global__ __launch_bounds__(256) void k_gemm2(
    const unsigned short* __restrict__ xcat,  // [256][3072] bf16
    const unsigned short* __restrict__ wcat,  // [2048][3072] bf16
    const float* __restrict__ bcat,           // [2048]
    float* __restrict__ S)                    // [256][2048]
{
    __shared__ unsigned short lA[64 * 64];    // 8 KB
    __shared__ unsigned short lB[128 * 64];   // 16 KB
    const int tid = threadIdx.x;
    const int w = tid >> 6, l = tid & 63;
    const int l16 = l & 15, lq = l >> 4;
    const int row0 = blockIdx.y * 64;
    const int col0 = blockIdx.x * 128;

    f32x4 acc[4][2];
    #pragma unroll
    for (int m = 0; m < 4; ++m)
        #pragma unroll
        for (int n = 0; n < 2; ++n) acc[m][n] = (f32x4){0.f, 0.f, 0.f, 0.f};

    for (int kt = 0; kt < 48; ++kt) {
        const int k0 = kt * 64;
        __syncthreads();
        #pragma unroll
        for (int i = 0; i < 2; ++i) {         // A: 512 chunks, 2/thread
            int g = tid + i*256;
            int r = g >> 3, q = g & 7;
            *(uint4*)&lA[r*64 + ((q ^ (r & 7)) * 8)] =
                *(const uint4*)(xcat + (size_t)(row0 + r)*3072 + k0 + q*8);
        }
        #pragma unroll
        for (int i = 0; i < 4; ++i) {         // B: 1024 chunks, 4/thread
            int g = tid + i*256;
            int r = g >> 3, q = g & 7;
            *(uint4*)&lB[r*64 + ((q ^ (r & 7)) * 8)] =
                *(const uint4*)(wcat + (size_t)(col0 + r)*3072 + k0 + q*8);
        }
        __syncthreads();

        #pragma unroll
        for (int kk = 0; kk < 2; ++kk) {
            const int c = kk*4 + lq;
            bf16x8 af[4];
            #pragma unroll
            for (int m = 0; m < 4; ++m) {
                int rr = m*16 + l16;
                af[m] = *(const bf16x8*)&lA[rr*64 + ((c ^ (rr & 7)) * 8)];
            }
            #pragma unroll
            for (int n = 0; n < 2; ++n) {
                int br = w*32 + n*16 + l16;
                bf16x8 bfr = *(const bf16x8*)&lB[br*64 + ((c ^ (br & 7)) * 8)];
                #pragma unroll
                for (int m = 0; m < 4; ++m)
                    acc[m][n] = __builtin_amdgcn_mfma_f32_16x16x32_bf16(af[m], bfr, acc[m][n], 0, 0, 0);
            }
        }
    }

    #pragma unroll
    for (int m = 0; m < 4; ++m)
        #pragma unroll
        for (int n = 0; n < 2; ++n)
            #pragma unroll
            for (int r = 0; r < 4; ++r) {
                int grow = row0 + m*16 + lq*4 + r;
                int col = col0 + w*32 + n*16 + l16;
                S[(size_t)grow*2048 + col] = acc[m][n][r] + bcat[col];
            }
}

// ---------------- LSTM gates ----------------
__global__ void k_lstm(const float* __restrict__ S, const float* __restrict__ prec,
                       float* __restrict__ out) {
    int b = blockIdx.x, h = threadIdx.x;  // 512 threads
    float ig = 1.f / (1.f + expf(-S[(size_t)b*2048 + h]));
    float fg = 1.f / (1.f + expf(-S[(size_t)b*2048 + 512 + h]));
    float og = 1.f / (1.f + expf(-S[(size_t)b*2048 + 1024 + h]));
    float gt = tanhf(S[(size_t)b*2048 + 1536 + h]);
    float c = fg * prec[b*512 + h] + ig * gt;
    out[b*512 + h] = og * tanhf(c);
    out[131072 + b*512 + h] = c;
}

// ---------------- launch ----------------
extern "C" void kernel_launch(void* const* d_in, const int* in_sizes, int n_in,
                              void* d_out, int out_size, void* d_ws, size_t ws_size,
                              hipStream_t stream) {
    const float* xt  = (const float*)d_in[0];
    const float* att = (const float*)d_in[1];
    const float* h0  = (const float*)d_in[2];
    const float* c0  = (const float*)d_in[3];
    const float* Wi  = (const float*)d_in[4];
    const float* bi  = (const float*)d_in[5];
    const float* Wh  = (const float*)d_in[6];
    const float* bh  = (const float*)d_in[7];
    const float* Wz  = (const float*)d_in[8];
    const float* bz  = (const float*)d_in[9];
    const float* Wa  = (const float*)d_in[10];
    const float* ba  = (const float*)d_in[11];
    const float* Wha = (const float*)d_in[12];
    const float* bha = (const float*)d_in[13];
    const float* Wo  = (const float*)d_in[14];
    const float* bo  = (const float*)d_in[15];
    float* out = (float*)d_out;

    char* ws = (char*)d_ws;
    unsigned short* wa_bf   = (unsigned short*)(ws);                       // 2 MB
    unsigned short* wcat_bf = (unsigned short*)(ws + 2097152);             // 12 MB
    unsigned short* xcat_bf = (unsigned short*)(ws + 14680064);            // 1.5 MB
    float* hlin   = (float*)(ws + 16252928);                               // 512 KB
    float* scores = (float*)(ws + 16777216);                               // 200 KB
    float* cw     = (float*)(ws + 16977920);                               // 200 KB
    float* bcat   = (float*)(ws + 17178624);                               // 8 KB
    float* S      = (float*)(ws + 17186816);                               // 2 MB

    k_cvt<<<1024, 256, 0, stream>>>(Wa, wa_bf, 262144);
    k_build_wcat<<<2048, 256, 0, stream>>>(Wi, Wh, Wz, bi, bh, bz, wcat_bf, bcat);
    k_build_xcat<<<256, 256, 0, stream>>>(xt, h0, xcat_bf);
    k_hlin<<<256, 512, 0, stream>>>(h0, Wha, bha, ba, hlin);
    k_scores<<<M_/128, 512, 0, stream>>>(att, wa_bf, hlin, Wo, bo, scores);
    k_softmax<<<256, 256, 0, stream>>>(scores, cw);
    k_z<<<dim3(2, 256), 256, 0, stream>>>(att, cw, xcat_bf);
    k_gemm2<<<dim3(16, 4), 256, 0, stream>>>(xcat_bf, wcat_bf, bcat, S);
    k_lstm<<<256, 512, 0, stream>>>(S, c0, out);
}